// Round 1
// baseline (1129.815 us; speedup 1.0000x reference)
//
#include <hip/hip_runtime.h>

// GraphSAGE 2-layer forward, fp32, N=100000 nodes, E=1.6M edges, D=128, out=40.
//
// Plan:
//   1. Build CSR by destination (deg count -> exclusive scan -> cursor fill).
//   2. agg1[n]  = mean_{s in nbr(n)} x[s]            (wave per node, float2/lane)
//   3. h1       = relu(x @ W1s + agg1 @ W1n + b1)    (vector-fp32 tiled GEMM, K=256 concat)
//   4. self2    -> out = h1 @ W2s ; t2 = h1 @ W2n    (one GEMM, 80 fused cols)
//   5. out[n]  += mean_{s in nbr(n)} t2[s] + b2      (aggregation AFTER transform: 40-dim)
//
// Aggregation-after-transform for layer 2 exploits linearity of segment-mean:
// cuts gather traffic from E*512B to E*160B.

#define WS_OFF_DEG      (0)
#define WS_OFF_ROWSTART (1 << 20)
#define WS_OFF_CURSOR   (2 << 20)
#define WS_OFF_CSR      (3 << 20)
#define WS_OFF_AGG1     (10 << 20)   // also reused for t2 after gemm1
#define WS_OFF_H1       (62 << 20)

// ---------------------------------------------------------------- CSR build

__global__ void deg_count(const int* __restrict__ dst, int* __restrict__ deg, int E) {
    int e = blockIdx.x * blockDim.x + threadIdx.x;
    if (e < E) atomicAdd(&deg[dst[e]], 1);
}

// Single-block exclusive scan over N=100000 degrees.
__global__ void scan_deg(const int* __restrict__ deg, int* __restrict__ row_start, int N) {
    __shared__ int sums[1024];
    int tid = threadIdx.x;
    int per = (N + 1023) / 1024;
    int start = tid * per;
    int end = min(start + per, N);
    int s = 0;
    for (int i = start; i < end; i++) s += deg[i];
    sums[tid] = s;
    __syncthreads();
    // naive log-step inclusive scan
    for (int off = 1; off < 1024; off <<= 1) {
        int v = (tid >= off) ? sums[tid - off] : 0;
        __syncthreads();
        sums[tid] += v;
        __syncthreads();
    }
    int base = (tid == 0) ? 0 : sums[tid - 1];
    for (int i = start; i < end; i++) { row_start[i] = base; base += deg[i]; }
    if (tid == 1023) row_start[N] = sums[1023];
}

__global__ void csr_fill(const int* __restrict__ src, const int* __restrict__ dst,
                         const int* __restrict__ row_start, int* __restrict__ cursor,
                         int* __restrict__ csr_src, int E) {
    int e = blockIdx.x * blockDim.x + threadIdx.x;
    if (e < E) {
        int d = dst[e];
        int slot = atomicAdd(&cursor[d], 1);
        csr_src[row_start[d] + slot] = src[e];
    }
}

// ------------------------------------------------------- aggregation kernels

// One wave per node; lane l owns features [2l, 2l+1] (float2) -> 512B coalesced row reads.
__global__ void agg_mean_128(const float* __restrict__ x, const int* __restrict__ row_start,
                             const int* __restrict__ csr_src, float* __restrict__ agg, int N) {
    int wave = (blockIdx.x * blockDim.x + threadIdx.x) >> 6;
    int lane = threadIdx.x & 63;
    if (wave >= N) return;
    int beg = row_start[wave], end = row_start[wave + 1];
    const float2* xf2 = (const float2*)x;
    float ax = 0.f, ay = 0.f;
    for (int e = beg; e < end; e++) {
        int s = csr_src[e];
        float2 v = xf2[s * 64 + lane];
        ax += v.x; ay += v.y;
    }
    float inv = 1.0f / fmaxf((float)(end - beg), 1.0f);
    float2 o; o.x = ax * inv; o.y = ay * inv;
    ((float2*)agg)[wave * 64 + lane] = o;
}

// One wave per node, 40 dims (lanes 0..39): out[n][c] += mean(t2[nbrs][c]) + b2[c]
__global__ void agg2_add(const float* __restrict__ t2, const int* __restrict__ row_start,
                         const int* __restrict__ csr_src, const float* __restrict__ b2,
                         float* __restrict__ out, int N) {
    int wave = (blockIdx.x * blockDim.x + threadIdx.x) >> 6;
    int lane = threadIdx.x & 63;
    if (wave >= N) return;
    int beg = row_start[wave], end = row_start[wave + 1];
    if (lane < 40) {
        float acc = 0.f;
        for (int e = beg; e < end; e++) {
            int s = csr_src[e];
            acc += t2[s * 40 + lane];
        }
        float inv = 1.0f / fmaxf((float)(end - beg), 1.0f);
        out[wave * 40 + lane] += acc * inv + b2[lane];
    }
}

// ------------------------------------------------------------------- GEMM 1
// h1 = relu(x @ W1s + agg @ W1n + b1), K=128 each (256 concat), 128 out cols.
// Block: 256 threads; tile 128 rows x 128 cols; thread tile 8x8; KC=16 chunks.

__global__ __launch_bounds__(256) void gemm1(
    const float* __restrict__ x, const float* __restrict__ agg,
    const float* __restrict__ Ws, const float* __restrict__ Wn,
    const float* __restrict__ b, float* __restrict__ h1, int N) {

    __shared__ float xs[128][17];
    __shared__ float as[128][17];
    __shared__ float ws[16][128];
    __shared__ float wn[16][128];

    int tid = threadIdx.x;
    int cg = tid & 15;    // col group: cols cg*8 .. cg*8+7
    int rg = tid >> 4;    // row group: rows rg*8 .. rg*8+7
    int row0 = blockIdx.x * 128;

    float acc[8][8];
#pragma unroll
    for (int i = 0; i < 8; i++)
#pragma unroll
        for (int j = 0; j < 8; j++) acc[i][j] = 0.f;

    for (int k0 = 0; k0 < 128; k0 += 16) {
        __syncthreads();
        // stage x / agg tile: thread t loads row t/2, k-offset (t&1)*8, 8 floats
        {
            int r = tid >> 1;
            int kk = (tid & 1) * 8;
            int row = row0 + r;
            float4 v0 = make_float4(0, 0, 0, 0), v1 = v0, a0 = v0, a1 = v0;
            if (row < N) {
                const float4* xp = (const float4*)(x + (size_t)row * 128 + k0 + kk);
                v0 = xp[0]; v1 = xp[1];
                const float4* ap = (const float4*)(agg + (size_t)row * 128 + k0 + kk);
                a0 = ap[0]; a1 = ap[1];
            }
            xs[r][kk + 0] = v0.x; xs[r][kk + 1] = v0.y; xs[r][kk + 2] = v0.z; xs[r][kk + 3] = v0.w;
            xs[r][kk + 4] = v1.x; xs[r][kk + 5] = v1.y; xs[r][kk + 6] = v1.z; xs[r][kk + 7] = v1.w;
            as[r][kk + 0] = a0.x; as[r][kk + 1] = a0.y; as[r][kk + 2] = a0.z; as[r][kk + 3] = a0.w;
            as[r][kk + 4] = a1.x; as[r][kk + 5] = a1.y; as[r][kk + 6] = a1.z; as[r][kk + 7] = a1.w;
        }
        // stage W chunks: thread t loads k-row t/16, cols (t&15)*8
        {
            int k = tid >> 4;
            int c = (tid & 15) * 8;
            const float4* p = (const float4*)(Ws + (size_t)(k0 + k) * 128 + c);
            float4 w0 = p[0], w1 = p[1];
            *(float4*)&ws[k][c] = w0; *(float4*)&ws[k][c + 4] = w1;
            const float4* q = (const float4*)(Wn + (size_t)(k0 + k) * 128 + c);
            float4 u0 = q[0], u1 = q[1];
            *(float4*)&wn[k][c] = u0; *(float4*)&wn[k][c + 4] = u1;
        }
        __syncthreads();

#pragma unroll
        for (int k = 0; k < 16; k++) {
            float xr[8], ar[8];
#pragma unroll
            for (int i = 0; i < 8; i++) {
                xr[i] = xs[rg * 8 + i][k];
                ar[i] = as[rg * 8 + i][k];
            }
            float4 w0 = *(const float4*)&ws[k][cg * 8];
            float4 w1 = *(const float4*)&ws[k][cg * 8 + 4];
            float4 u0 = *(const float4*)&wn[k][cg * 8];
            float4 u1 = *(const float4*)&wn[k][cg * 8 + 4];
            float wv[8] = {w0.x, w0.y, w0.z, w0.w, w1.x, w1.y, w1.z, w1.w};
            float uv[8] = {u0.x, u0.y, u0.z, u0.w, u1.x, u1.y, u1.z, u1.w};
#pragma unroll
            for (int i = 0; i < 8; i++)
#pragma unroll
                for (int j = 0; j < 8; j++)
                    acc[i][j] += xr[i] * wv[j] + ar[i] * uv[j];
        }
    }

    // epilogue: + b1, relu, store
#pragma unroll
    for (int i = 0; i < 8; i++) {
        int row = row0 + rg * 8 + i;
        if (row < N) {
            float4 o0, o1;
            o0.x = fmaxf(acc[i][0] + b[cg * 8 + 0], 0.f);
            o0.y = fmaxf(acc[i][1] + b[cg * 8 + 1], 0.f);
            o0.z = fmaxf(acc[i][2] + b[cg * 8 + 2], 0.f);
            o0.w = fmaxf(acc[i][3] + b[cg * 8 + 3], 0.f);
            o1.x = fmaxf(acc[i][4] + b[cg * 8 + 4], 0.f);
            o1.y = fmaxf(acc[i][5] + b[cg * 8 + 5], 0.f);
            o1.z = fmaxf(acc[i][6] + b[cg * 8 + 6], 0.f);
            o1.w = fmaxf(acc[i][7] + b[cg * 8 + 7], 0.f);
            *(float4*)(h1 + (size_t)row * 128 + cg * 8) = o0;
            *(float4*)(h1 + (size_t)row * 128 + cg * 8 + 4) = o1;
        }
    }
}

// ------------------------------------------------------------------- GEMM 2
// out(self part) = h1 @ W2s ; t2 = h1 @ W2n.  80 fused output cols (2x40).
// Block: 320 threads (5 waves); tile 256 rows x 80 cols; thread tile 8x8.

__global__ __launch_bounds__(320) void gemm2(
    const float* __restrict__ h1, const float* __restrict__ W2s,
    const float* __restrict__ W2n, float* __restrict__ out,
    float* __restrict__ t2, int N) {

    __shared__ float hs[256][17];
    __shared__ float wcat[16][80];   // cols 0..39 = W2s, 40..79 = W2n

    int tid = threadIdx.x;
    int cg = tid % 10;   // col group: fused cols cg*8 .. cg*8+7
    int rg = tid / 10;   // row group 0..31
    int row0 = blockIdx.x * 256;

    float acc[8][8];
#pragma unroll
    for (int i = 0; i < 8; i++)
#pragma unroll
        for (int j = 0; j < 8; j++) acc[i][j] = 0.f;

    for (int k0 = 0; k0 < 128; k0 += 16) {
        __syncthreads();
        for (int idx = tid; idx < 1024; idx += 320) {   // 256x16 floats as float4s
            int r = idx >> 2;
            int kk = (idx & 3) * 4;
            int row = row0 + r;
            float4 v = make_float4(0, 0, 0, 0);
            if (row < N) v = *(const float4*)(h1 + (size_t)row * 128 + k0 + kk);
            hs[r][kk + 0] = v.x; hs[r][kk + 1] = v.y; hs[r][kk + 2] = v.z; hs[r][kk + 3] = v.w;
        }
        for (int idx = tid; idx < 1280; idx += 320) {   // 16x80
            int k = idx / 80;
            int c = idx % 80;
            wcat[k][c] = (c < 40) ? W2s[(size_t)(k0 + k) * 40 + c]
                                  : W2n[(size_t)(k0 + k) * 40 + (c - 40)];
        }
        __syncthreads();

#pragma unroll
        for (int k = 0; k < 16; k++) {
            float hr[8];
#pragma unroll
            for (int i = 0; i < 8; i++) hr[i] = hs[rg * 8 + i][k];
            float4 w0 = *(const float4*)&wcat[k][cg * 8];
            float4 w1 = *(const float4*)&wcat[k][cg * 8 + 4];
            float wv[8] = {w0.x, w0.y, w0.z, w0.w, w1.x, w1.y, w1.z, w1.w};
#pragma unroll
            for (int i = 0; i < 8; i++)
#pragma unroll
                for (int j = 0; j < 8; j++)
                    acc[i][j] += hr[i] * wv[j];
        }
    }

    bool isSelf = (cg < 5);
    int cbase = (isSelf ? cg : cg - 5) * 8;
    float* dstp = isSelf ? out : t2;
#pragma unroll
    for (int i = 0; i < 8; i++) {
        int row = row0 + rg * 8 + i;
        if (row < N) {
            float4 o0, o1;
            o0.x = acc[i][0]; o0.y = acc[i][1]; o0.z = acc[i][2]; o0.w = acc[i][3];
            o1.x = acc[i][4]; o1.y = acc[i][5]; o1.z = acc[i][6]; o1.w = acc[i][7];
            *(float4*)(dstp + (size_t)row * 40 + cbase) = o0;
            *(float4*)(dstp + (size_t)row * 40 + cbase + 4) = o1;
        }
    }
}

// ------------------------------------------------------------------ launch

extern "C" void kernel_launch(void* const* d_in, const int* in_sizes, int n_in,
                              void* d_out, int out_size, void* d_ws, size_t ws_size,
                              hipStream_t stream) {
    const float* x   = (const float*)d_in[0];
    const int*   src = (const int*)d_in[1];
    const int*   dst = (const int*)d_in[2];
    const float* W1s = (const float*)d_in[3];
    const float* W1n = (const float*)d_in[4];
    const float* b1  = (const float*)d_in[5];
    const float* W2s = (const float*)d_in[6];
    const float* W2n = (const float*)d_in[7];
    const float* b2  = (const float*)d_in[8];
    float* out = (float*)d_out;

    int N = in_sizes[0] / 128;
    int E = in_sizes[1];

    char* ws = (char*)d_ws;
    int*   deg       = (int*)(ws + WS_OFF_DEG);
    int*   row_start = (int*)(ws + WS_OFF_ROWSTART);
    int*   cursor    = (int*)(ws + WS_OFF_CURSOR);
    int*   csr_src   = (int*)(ws + WS_OFF_CSR);
    float* agg1      = (float*)(ws + WS_OFF_AGG1);
    float* t2        = (float*)(ws + WS_OFF_AGG1);  // reuse: agg1 dead after gemm1
    float* h1        = (float*)(ws + WS_OFF_H1);

    hipMemsetAsync(deg, 0, (size_t)N * sizeof(int), stream);
    hipMemsetAsync(cursor, 0, (size_t)N * sizeof(int), stream);

    deg_count<<<(E + 255) / 256, 256, 0, stream>>>(dst, deg, E);
    scan_deg<<<1, 1024, 0, stream>>>(deg, row_start, N);
    csr_fill<<<(E + 255) / 256, 256, 0, stream>>>(src, dst, row_start, cursor, csr_src, E);

    // layer 1
    int aggBlocks = (N * 64 + 255) / 256;
    agg_mean_128<<<aggBlocks, 256, 0, stream>>>(x, row_start, csr_src, agg1, N);
    gemm1<<<(N + 127) / 128, 256, 0, stream>>>(x, agg1, W1s, W1n, b1, h1, N);

    // layer 2 (transform-then-aggregate)
    gemm2<<<(N + 255) / 256, 320, 0, stream>>>(h1, W2s, W2n, out, t2, N);
    agg2_add<<<aggBlocks, 256, 0, stream>>>(t2, row_start, csr_src, b2, out, N);
}

// Round 2
// 781.963 us; speedup vs baseline: 1.4448x; 1.4448x over previous
//
#include <hip/hip_runtime.h>

// GraphSAGE 2-layer forward on MI355X.
// Round 2: bf16 MFMA GEMMs + bf16 gather.
//   1. CSR build by destination (unchanged).
//   2. cast x -> bf16; pre-transpose weights to [col][k] bf16.
//   3. agg1[n] = mean_{s in nbr(n)} xb[s]   (bf16 gather, fp32 accum, bf16 out)
//   4. h1 = relu([xb|aggb] @ [W1s;W1n] + b1)  -- MFMA 16x16x32 bf16, K=256
//   5. [out_self | t2] = h1 @ [W2s|W2n]       -- MFMA, 80 fused cols
//   6. out[n] += mean_{s in nbr(n)} t2[s] + b2  (aggregate AFTER transform: 40-dim)

typedef __attribute__((ext_vector_type(8))) short bf16x8;
typedef __attribute__((ext_vector_type(4))) float f32x4;

#define OFF_DEG      (0u)
#define OFF_ROWSTART (1u << 20)
#define OFF_CURSOR   (2u << 20)
#define OFF_CSR      (3u << 20)    // 6.4 MB
#define OFF_W1T      (10u << 20)   // 64 KB  [128 cols][256 k] bf16
#define OFF_W2T      (11u << 20)   // 20 KB  [80 cols][128 k] bf16
#define OFF_XB       (12u << 20)   // 25.6 MB
#define OFF_AGGB     (40u << 20)   // 25.6 MB
#define OFF_H1B      (68u << 20)   // 25.6 MB
#define OFF_T2       (96u << 20)   // 16 MB

static __device__ __forceinline__ unsigned short f2b(float f) {
    unsigned int u = __float_as_uint(f);
    u += 0x7fffu + ((u >> 16) & 1u);   // round-to-nearest-even
    return (unsigned short)(u >> 16);
}
static __device__ __forceinline__ float blo(unsigned int v) { return __uint_as_float(v << 16); }
static __device__ __forceinline__ float bhi(unsigned int v) { return __uint_as_float(v & 0xffff0000u); }

// ---------------------------------------------------------------- CSR build

__global__ void deg_count(const int* __restrict__ dst, int* __restrict__ deg, int E) {
    int e = blockIdx.x * blockDim.x + threadIdx.x;
    if (e < E) atomicAdd(&deg[dst[e]], 1);
}

__global__ void scan_deg(const int* __restrict__ deg, int* __restrict__ row_start, int N) {
    __shared__ int sums[1024];
    int tid = threadIdx.x;
    int per = (N + 1023) / 1024;
    int start = tid * per;
    int end = min(start + per, N);
    int s = 0;
    for (int i = start; i < end; i++) s += deg[i];
    sums[tid] = s;
    __syncthreads();
    for (int off = 1; off < 1024; off <<= 1) {
        int v = (tid >= off) ? sums[tid - off] : 0;
        __syncthreads();
        sums[tid] += v;
        __syncthreads();
    }
    int base = (tid == 0) ? 0 : sums[tid - 1];
    for (int i = start; i < end; i++) { row_start[i] = base; base += deg[i]; }
    if (tid == 1023) row_start[N] = sums[1023];
}

__global__ void csr_fill(const int* __restrict__ src, const int* __restrict__ dst,
                         const int* __restrict__ row_start, int* __restrict__ cursor,
                         int* __restrict__ csr_src, int E) {
    int e = blockIdx.x * blockDim.x + threadIdx.x;
    if (e < E) {
        int d = dst[e];
        int slot = atomicAdd(&cursor[d], 1);
        csr_src[row_start[d] + slot] = src[e];
    }
}

// ------------------------------------------------------------- prep kernels

__global__ void cast_bf16(const float* __restrict__ x, unsigned short* __restrict__ xb, int n8) {
    int i = blockIdx.x * blockDim.x + threadIdx.x;
    if (i >= n8) return;
    const float4* p = (const float4*)x + (size_t)i * 2;
    float4 v0 = p[0], v1 = p[1];
    unsigned short o[8];
    o[0] = f2b(v0.x); o[1] = f2b(v0.y); o[2] = f2b(v0.z); o[3] = f2b(v0.w);
    o[4] = f2b(v1.x); o[5] = f2b(v1.y); o[6] = f2b(v1.z); o[7] = f2b(v1.w);
    *(float4*)(xb + (size_t)i * 8) = *(float4*)o;
}

// W1t[c][k]: k<128 -> W1s[k][c], else W1n[k-128][c].  <<<128, 256>>>
__global__ void prep_w1t(const float* __restrict__ W1s, const float* __restrict__ W1n,
                         unsigned short* __restrict__ W1t) {
    int c = blockIdx.x, k = threadIdx.x;
    float v = (k < 128) ? W1s[(size_t)k * 128 + c] : W1n[(size_t)(k - 128) * 128 + c];
    W1t[(size_t)c * 256 + k] = f2b(v);
}

// W2t[c][k]: c<40 -> W2s[k][c], else W2n[k][c-40].  <<<80, 128>>>
__global__ void prep_w2t(const float* __restrict__ W2s, const float* __restrict__ W2n,
                         unsigned short* __restrict__ W2t) {
    int c = blockIdx.x, k = threadIdx.x;
    float v = (c < 40) ? W2s[(size_t)k * 40 + c] : W2n[(size_t)k * 40 + (c - 40)];
    W2t[(size_t)c * 128 + k] = f2b(v);
}

// ------------------------------------------------------- aggregation kernels

// One wave per node; lane l owns dims [2l, 2l+1] (one uint = 2 bf16).
__global__ void agg_mean_bf16(const unsigned short* __restrict__ xb,
                              const int* __restrict__ row_start,
                              const int* __restrict__ csr_src,
                              unsigned short* __restrict__ aggb, int N) {
    int wave = (blockIdx.x * blockDim.x + threadIdx.x) >> 6;
    int lane = threadIdx.x & 63;
    if (wave >= N) return;
    int beg = row_start[wave], end = row_start[wave + 1];
    const unsigned int* x2 = (const unsigned int*)xb;
    float ax = 0.f, ay = 0.f;
    for (int e = beg; e < end; e++) {
        int s = csr_src[e];
        unsigned int v = x2[(size_t)s * 64 + lane];
        ax += blo(v); ay += bhi(v);
    }
    float inv = 1.0f / fmaxf((float)(end - beg), 1.0f);
    unsigned int o = (unsigned int)f2b(ax * inv) | ((unsigned int)f2b(ay * inv) << 16);
    ((unsigned int*)aggb)[(size_t)wave * 64 + lane] = o;
}

// One wave per node, 40 dims: out[n][c] += mean(t2[nbrs][c]) + b2[c]
__global__ void agg2_add(const float* __restrict__ t2, const int* __restrict__ row_start,
                         const int* __restrict__ csr_src, const float* __restrict__ b2,
                         float* __restrict__ out, int N) {
    int wave = (blockIdx.x * blockDim.x + threadIdx.x) >> 6;
    int lane = threadIdx.x & 63;
    if (wave >= N) return;
    int beg = row_start[wave], end = row_start[wave + 1];
    if (lane < 40) {
        float acc = 0.f;
        for (int e = beg; e < end; e++) {
            int s = csr_src[e];
            acc += t2[(size_t)s * 40 + lane];
        }
        float inv = 1.0f / fmaxf((float)(end - beg), 1.0f);
        out[(size_t)wave * 40 + lane] += acc * inv + b2[lane];
    }
}

// ------------------------------------------------------------------- GEMM 1
// h1 = relu([xb|aggb] @ W1cat + b1); K=256, 128 cols. MFMA 16x16x32 bf16.
// Block 256 thr (4 waves); tile 128 rows x 128 cols; wave: 32 rows x 128 cols.
// LDS stride 40 ushorts (80 B): 16B-aligned rows, <=2-way bank aliasing (free).

__global__ __launch_bounds__(256) void gemm1_mfma(
    const unsigned short* __restrict__ xb, const unsigned short* __restrict__ aggb,
    const unsigned short* __restrict__ W1t, const float* __restrict__ b1,
    unsigned short* __restrict__ h1, int N) {

    __shared__ unsigned short As[128 * 40];  // 128 rows x 32 k (+8 pad)
    __shared__ unsigned short Bs[128 * 40];  // 128 cols x 32 k (+8 pad)

    int tid = threadIdx.x;
    int wave = tid >> 6, lane = tid & 63;
    int row0 = blockIdx.x * 128;
    int m = lane & 15, quad = lane >> 4;

    f32x4 acc[2][8];
#pragma unroll
    for (int i = 0; i < 2; i++)
#pragma unroll
        for (int j = 0; j < 8; j++) acc[i][j] = (f32x4){0.f, 0.f, 0.f, 0.f};

    for (int k0 = 0; k0 < 256; k0 += 32) {
        __syncthreads();
        {
            int r = tid >> 1, kk = (tid & 1) * 16;
            int row = row0 + r;
            float4 v0 = make_float4(0, 0, 0, 0), v1 = v0;
            if (row < N) {
                const unsigned short* s = (k0 < 128)
                    ? (xb + (size_t)row * 128 + k0 + kk)
                    : (aggb + (size_t)row * 128 + (k0 - 128) + kk);
                const float4* p = (const float4*)s;
                v0 = p[0]; v1 = p[1];
            }
            *(float4*)&As[r * 40 + kk] = v0;
            *(float4*)&As[r * 40 + kk + 8] = v1;
            const float4* q = (const float4*)(W1t + (size_t)r * 256 + k0 + kk);
            float4 w0 = q[0], w1 = q[1];
            *(float4*)&Bs[r * 40 + kk] = w0;
            *(float4*)&Bs[r * 40 + kk + 8] = w1;
        }
        __syncthreads();

        bf16x8 af0 = *(bf16x8*)&As[(wave * 32 + m) * 40 + quad * 8];
        bf16x8 af1 = *(bf16x8*)&As[(wave * 32 + 16 + m) * 40 + quad * 8];
#pragma unroll
        for (int j = 0; j < 8; j++) {
            bf16x8 bfg = *(bf16x8*)&Bs[(j * 16 + m) * 40 + quad * 8];
            acc[0][j] = __builtin_amdgcn_mfma_f32_16x16x32_bf16(af0, bfg, acc[0][j], 0, 0, 0);
            acc[1][j] = __builtin_amdgcn_mfma_f32_16x16x32_bf16(af1, bfg, acc[1][j], 0, 0, 0);
        }
    }

    // epilogue: +b1, relu, bf16 store.  C/D: col = lane&15, row = quad*4+reg.
#pragma unroll
    for (int j = 0; j < 8; j++) {
        int col = j * 16 + m;
        float bias = b1[col];
#pragma unroll
        for (int i = 0; i < 2; i++) {
#pragma unroll
            for (int r = 0; r < 4; r++) {
                int row = row0 + wave * 32 + i * 16 + quad * 4 + r;
                if (row < N) {
                    float v = fmaxf(acc[i][j][r] + bias, 0.f);
                    h1[(size_t)row * 128 + col] = f2b(v);
                }
            }
        }
    }
}

// ------------------------------------------------------------------- GEMM 2
// [out_self | t2] = h1 @ W2cat; K=128, 80 fused cols. Tile 128 rows x 80 cols.

__global__ __launch_bounds__(256) void gemm2_mfma(
    const unsigned short* __restrict__ h1, const unsigned short* __restrict__ W2t,
    float* __restrict__ out, float* __restrict__ t2, int N) {

    __shared__ unsigned short As[128 * 40];  // 128 rows x 32 k
    __shared__ unsigned short Bs[80 * 40];   // 80 cols x 32 k

    int tid = threadIdx.x;
    int wave = tid >> 6, lane = tid & 63;
    int row0 = blockIdx.x * 128;
    int m = lane & 15, quad = lane >> 4;

    f32x4 acc[2][5];
#pragma unroll
    for (int i = 0; i < 2; i++)
#pragma unroll
        for (int j = 0; j < 5; j++) acc[i][j] = (f32x4){0.f, 0.f, 0.f, 0.f};

    for (int k0 = 0; k0 < 128; k0 += 32) {
        __syncthreads();
        {
            int r = tid >> 1, kk = (tid & 1) * 16;
            int row = row0 + r;
            float4 v0 = make_float4(0, 0, 0, 0), v1 = v0;
            if (row < N) {
                const float4* p = (const float4*)(h1 + (size_t)row * 128 + k0 + kk);
                v0 = p[0]; v1 = p[1];
            }
            *(float4*)&As[r * 40 + kk] = v0;
            *(float4*)&As[r * 40 + kk + 8] = v1;
            if (tid < 160) {
                const float4* q = (const float4*)(W2t + (size_t)r * 128 + k0 + kk);
                float4 w0 = q[0], w1 = q[1];
                *(float4*)&Bs[r * 40 + kk] = w0;
                *(float4*)&Bs[r * 40 + kk + 8] = w1;
            }
        }
        __syncthreads();

        bf16x8 af0 = *(bf16x8*)&As[(wave * 32 + m) * 40 + quad * 8];
        bf16x8 af1 = *(bf16x8*)&As[(wave * 32 + 16 + m) * 40 + quad * 8];
#pragma unroll
        for (int j = 0; j < 5; j++) {
            bf16x8 bfg = *(bf16x8*)&Bs[(j * 16 + m) * 40 + quad * 8];
            acc[0][j] = __builtin_amdgcn_mfma_f32_16x16x32_bf16(af0, bfg, acc[0][j], 0, 0, 0);
            acc[1][j] = __builtin_amdgcn_mfma_f32_16x16x32_bf16(af1, bfg, acc[1][j], 0, 0, 0);
        }
    }

#pragma unroll
    for (int j = 0; j < 5; j++) {
        int col = j * 16 + m;
#pragma unroll
        for (int i = 0; i < 2; i++) {
#pragma unroll
            for (int r = 0; r < 4; r++) {
                int row = row0 + wave * 32 + i * 16 + quad * 4 + r;
                if (row < N) {
                    float v = acc[i][j][r];
                    if (col < 40) out[(size_t)row * 40 + col] = v;
                    else          t2[(size_t)row * 40 + (col - 40)] = v;
                }
            }
        }
    }
}

// ------------------------------------------------------------------ launch

extern "C" void kernel_launch(void* const* d_in, const int* in_sizes, int n_in,
                              void* d_out, int out_size, void* d_ws, size_t ws_size,
                              hipStream_t stream) {
    const float* x   = (const float*)d_in[0];
    const int*   src = (const int*)d_in[1];
    const int*   dst = (const int*)d_in[2];
    const float* W1s = (const float*)d_in[3];
    const float* W1n = (const float*)d_in[4];
    const float* b1  = (const float*)d_in[5];
    const float* W2s = (const float*)d_in[6];
    const float* W2n = (const float*)d_in[7];
    const float* b2  = (const float*)d_in[8];
    float* out = (float*)d_out;

    int N = in_sizes[0] / 128;
    int E = in_sizes[1];

    char* ws = (char*)d_ws;
    int*            deg       = (int*)(ws + OFF_DEG);
    int*            row_start = (int*)(ws + OFF_ROWSTART);
    int*            cursor    = (int*)(ws + OFF_CURSOR);
    int*            csr_src   = (int*)(ws + OFF_CSR);
    unsigned short* W1t       = (unsigned short*)(ws + OFF_W1T);
    unsigned short* W2t       = (unsigned short*)(ws + OFF_W2T);
    unsigned short* xb        = (unsigned short*)(ws + OFF_XB);
    unsigned short* aggb      = (unsigned short*)(ws + OFF_AGGB);
    unsigned short* h1b       = (unsigned short*)(ws + OFF_H1B);
    float*          t2        = (float*)(ws + OFF_T2);

    hipMemsetAsync(deg, 0, (size_t)N * sizeof(int), stream);
    hipMemsetAsync(cursor, 0, (size_t)N * sizeof(int), stream);

    deg_count<<<(E + 255) / 256, 256, 0, stream>>>(dst, deg, E);
    scan_deg<<<1, 1024, 0, stream>>>(deg, row_start, N);
    csr_fill<<<(E + 255) / 256, 256, 0, stream>>>(src, dst, row_start, cursor, csr_src, E);

    int n8 = N * 128 / 8;
    cast_bf16<<<(n8 + 255) / 256, 256, 0, stream>>>(x, xb, n8);
    prep_w1t<<<128, 256, 0, stream>>>(W1s, W1n, W1t);
    prep_w2t<<<80, 128, 0, stream>>>(W2s, W2n, W2t);

    int aggBlocks = (N * 64 + 255) / 256;
    agg_mean_bf16<<<aggBlocks, 256, 0, stream>>>(xb, row_start, csr_src, aggb, N);
    gemm1_mfma<<<(N + 127) / 128, 256, 0, stream>>>(xb, aggb, W1t, b1, h1b, N);
    gemm2_mfma<<<(N + 127) / 128, 256, 0, stream>>>(h1b, W2t, out, t2, N);
    agg2_add<<<aggBlocks, 256, 0, stream>>>(t2, row_start, csr_src, b2, out, N);
}

// Round 3
// 613.824 us; speedup vs baseline: 1.8406x; 1.2739x over previous
//
#include <hip/hip_runtime.h>

// GraphSAGE 2-layer forward on MI355X.
// Round 3: replace single-block degree scan (159 us, 0.16% occupancy) with
// a 3-kernel hierarchical scan (~10 us). Rest unchanged from round 2:
//   1. CSR build by destination (deg count -> hierarchical scan -> cursor fill).
//   2. cast x -> bf16; pre-transpose weights to [col][k] bf16.
//   3. agg1[n] = mean_{s in nbr(n)} xb[s]   (bf16 gather, fp32 accum, bf16 out)
//   4. h1 = relu([xb|aggb] @ [W1s;W1n] + b1)  -- MFMA 16x16x32 bf16, K=256
//   5. [out_self | t2] = h1 @ [W2s|W2n]       -- MFMA, 80 fused cols
//   6. out[n] += mean_{s in nbr(n)} t2[s] + b2  (aggregate AFTER transform)

typedef __attribute__((ext_vector_type(8))) short bf16x8;
typedef __attribute__((ext_vector_type(4))) float f32x4;

#define OFF_DEG      (0ull)
#define OFF_ROWSTART (1ull << 20)
#define OFF_CURSOR   (2ull << 20)
#define OFF_TMP      (3ull << 20)                      // 400 KB per-elem local prefix
#define OFF_BSUMS    ((3ull << 20) + (512ull << 10))   // block sums (~2 KB)
#define OFF_BOFFS    ((3ull << 20) + (576ull << 10))   // block offsets (~2 KB)
#define OFF_CSR      (4ull << 20)                      // 6.4 MB
#define OFF_W1T      (11ull << 20)                     // 64 KB  [128 cols][256 k] bf16
#define OFF_W2T      (12ull << 20)                     // 20 KB  [80 cols][128 k] bf16
#define OFF_XB       (13ull << 20)                     // 25.6 MB
#define OFF_AGGB     (39ull << 20)                     // 25.6 MB
#define OFF_H1B      (65ull << 20)                     // 25.6 MB
#define OFF_T2       (91ull << 20)                     // 16 MB

static __device__ __forceinline__ unsigned short f2b(float f) {
    unsigned int u = __float_as_uint(f);
    u += 0x7fffu + ((u >> 16) & 1u);   // round-to-nearest-even
    return (unsigned short)(u >> 16);
}
static __device__ __forceinline__ float blo(unsigned int v) { return __uint_as_float(v << 16); }
static __device__ __forceinline__ float bhi(unsigned int v) { return __uint_as_float(v & 0xffff0000u); }

// ---------------------------------------------------------------- CSR build

__global__ void deg_count(const int* __restrict__ dst, int* __restrict__ deg, int E) {
    int e = blockIdx.x * blockDim.x + threadIdx.x;
    if (e < E) atomicAdd(&deg[dst[e]], 1);
}

// Hierarchical exclusive scan, pass 1: per-block (256-wide) local scan.
__global__ void scan1(const int* __restrict__ deg, int* __restrict__ tmp,
                      int* __restrict__ bsums, int N) {
    __shared__ int s[256];
    int t = threadIdx.x;
    int i = blockIdx.x * 256 + t;
    int v = (i < N) ? deg[i] : 0;
    s[t] = v;
    __syncthreads();
    for (int off = 1; off < 256; off <<= 1) {
        int u = (t >= off) ? s[t - off] : 0;
        __syncthreads();
        s[t] += u;
        __syncthreads();
    }
    if (i < N) tmp[i] = s[t] - v;               // exclusive local prefix
    if (t == 255) bsums[blockIdx.x] = s[t];
}

// Pass 2: single small block scans the block sums (nb <= 512).
__global__ void scan2(const int* __restrict__ bsums, int* __restrict__ boffs, int nb) {
    __shared__ int s[512];
    int t = threadIdx.x;
    int v = (t < nb) ? bsums[t] : 0;
    s[t] = v;
    __syncthreads();
    for (int off = 1; off < 512; off <<= 1) {
        int u = (t >= off) ? s[t - off] : 0;
        __syncthreads();
        s[t] += u;
        __syncthreads();
    }
    if (t < nb) boffs[t] = s[t] - v;            // exclusive
    if (t == 511) boffs[nb] = s[t];             // grand total
}

// Pass 3: add block offsets.
__global__ void scan3(const int* __restrict__ tmp, const int* __restrict__ boffs,
                      int* __restrict__ row_start, int N, int nb) {
    int i = blockIdx.x * 256 + threadIdx.x;
    if (i < N) row_start[i] = tmp[i] + boffs[blockIdx.x];
    if (i == 0) row_start[N] = boffs[nb];
}

__global__ void csr_fill(const int* __restrict__ src, const int* __restrict__ dst,
                         const int* __restrict__ row_start, int* __restrict__ cursor,
                         int* __restrict__ csr_src, int E) {
    int e = blockIdx.x * blockDim.x + threadIdx.x;
    if (e < E) {
        int d = dst[e];
        int slot = atomicAdd(&cursor[d], 1);
        csr_src[row_start[d] + slot] = src[e];
    }
}

// ------------------------------------------------------------- prep kernels

__global__ void cast_bf16(const float* __restrict__ x, unsigned short* __restrict__ xb, int n8) {
    int i = blockIdx.x * blockDim.x + threadIdx.x;
    if (i >= n8) return;
    const float4* p = (const float4*)x + (size_t)i * 2;
    float4 v0 = p[0], v1 = p[1];
    unsigned short o[8];
    o[0] = f2b(v0.x); o[1] = f2b(v0.y); o[2] = f2b(v0.z); o[3] = f2b(v0.w);
    o[4] = f2b(v1.x); o[5] = f2b(v1.y); o[6] = f2b(v1.z); o[7] = f2b(v1.w);
    *(float4*)(xb + (size_t)i * 8) = *(float4*)o;
}

// W1t[c][k]: k<128 -> W1s[k][c], else W1n[k-128][c].  <<<128, 256>>>
__global__ void prep_w1t(const float* __restrict__ W1s, const float* __restrict__ W1n,
                         unsigned short* __restrict__ W1t) {
    int c = blockIdx.x, k = threadIdx.x;
    float v = (k < 128) ? W1s[(size_t)k * 128 + c] : W1n[(size_t)(k - 128) * 128 + c];
    W1t[(size_t)c * 256 + k] = f2b(v);
}

// W2t[c][k]: c<40 -> W2s[k][c], else W2n[k][c-40].  <<<80, 128>>>
__global__ void prep_w2t(const float* __restrict__ W2s, const float* __restrict__ W2n,
                         unsigned short* __restrict__ W2t) {
    int c = blockIdx.x, k = threadIdx.x;
    float v = (c < 40) ? W2s[(size_t)k * 40 + c] : W2n[(size_t)k * 40 + (c - 40)];
    W2t[(size_t)c * 128 + k] = f2b(v);
}

// ------------------------------------------------------- aggregation kernels

// One wave per node; lane l owns dims [2l, 2l+1] (one uint = 2 bf16).
__global__ void agg_mean_bf16(const unsigned short* __restrict__ xb,
                              const int* __restrict__ row_start,
                              const int* __restrict__ csr_src,
                              unsigned short* __restrict__ aggb, int N) {
    int wave = (blockIdx.x * blockDim.x + threadIdx.x) >> 6;
    int lane = threadIdx.x & 63;
    if (wave >= N) return;
    int beg = row_start[wave], end = row_start[wave + 1];
    const unsigned int* x2 = (const unsigned int*)xb;
    float ax = 0.f, ay = 0.f;
    for (int e = beg; e < end; e++) {
        int s = csr_src[e];
        unsigned int v = x2[(size_t)s * 64 + lane];
        ax += blo(v); ay += bhi(v);
    }
    float inv = 1.0f / fmaxf((float)(end - beg), 1.0f);
    unsigned int o = (unsigned int)f2b(ax * inv) | ((unsigned int)f2b(ay * inv) << 16);
    ((unsigned int*)aggb)[(size_t)wave * 64 + lane] = o;
}

// One wave per node, 40 dims: out[n][c] += mean(t2[nbrs][c]) + b2[c]
__global__ void agg2_add(const float* __restrict__ t2, const int* __restrict__ row_start,
                         const int* __restrict__ csr_src, const float* __restrict__ b2,
                         float* __restrict__ out, int N) {
    int wave = (blockIdx.x * blockDim.x + threadIdx.x) >> 6;
    int lane = threadIdx.x & 63;
    if (wave >= N) return;
    int beg = row_start[wave], end = row_start[wave + 1];
    if (lane < 40) {
        float acc = 0.f;
        for (int e = beg; e < end; e++) {
            int s = csr_src[e];
            acc += t2[(size_t)s * 40 + lane];
        }
        float inv = 1.0f / fmaxf((float)(end - beg), 1.0f);
        out[(size_t)wave * 40 + lane] += acc * inv + b2[lane];
    }
}

// ------------------------------------------------------------------- GEMM 1
// h1 = relu([xb|aggb] @ W1cat + b1); K=256, 128 cols. MFMA 16x16x32 bf16.
// Block 256 thr (4 waves); tile 128 rows x 128 cols; wave: 32 rows x 128 cols.
// LDS stride 40 ushorts (80 B): 16B-aligned rows, <=2-way bank aliasing (free).

__global__ __launch_bounds__(256) void gemm1_mfma(
    const unsigned short* __restrict__ xb, const unsigned short* __restrict__ aggb,
    const unsigned short* __restrict__ W1t, const float* __restrict__ b1,
    unsigned short* __restrict__ h1, int N) {

    __shared__ unsigned short As[128 * 40];  // 128 rows x 32 k (+8 pad)
    __shared__ unsigned short Bs[128 * 40];  // 128 cols x 32 k (+8 pad)

    int tid = threadIdx.x;
    int wave = tid >> 6, lane = tid & 63;
    int row0 = blockIdx.x * 128;
    int m = lane & 15, quad = lane >> 4;

    f32x4 acc[2][8];
#pragma unroll
    for (int i = 0; i < 2; i++)
#pragma unroll
        for (int j = 0; j < 8; j++) acc[i][j] = (f32x4){0.f, 0.f, 0.f, 0.f};

    for (int k0 = 0; k0 < 256; k0 += 32) {
        __syncthreads();
        {
            int r = tid >> 1, kk = (tid & 1) * 16;
            int row = row0 + r;
            float4 v0 = make_float4(0, 0, 0, 0), v1 = v0;
            if (row < N) {
                const unsigned short* s = (k0 < 128)
                    ? (xb + (size_t)row * 128 + k0 + kk)
                    : (aggb + (size_t)row * 128 + (k0 - 128) + kk);
                const float4* p = (const float4*)s;
                v0 = p[0]; v1 = p[1];
            }
            *(float4*)&As[r * 40 + kk] = v0;
            *(float4*)&As[r * 40 + kk + 8] = v1;
            const float4* q = (const float4*)(W1t + (size_t)r * 256 + k0 + kk);
            float4 w0 = q[0], w1 = q[1];
            *(float4*)&Bs[r * 40 + kk] = w0;
            *(float4*)&Bs[r * 40 + kk + 8] = w1;
        }
        __syncthreads();

        bf16x8 af0 = *(bf16x8*)&As[(wave * 32 + m) * 40 + quad * 8];
        bf16x8 af1 = *(bf16x8*)&As[(wave * 32 + 16 + m) * 40 + quad * 8];
#pragma unroll
        for (int j = 0; j < 8; j++) {
            bf16x8 bfg = *(bf16x8*)&Bs[(j * 16 + m) * 40 + quad * 8];
            acc[0][j] = __builtin_amdgcn_mfma_f32_16x16x32_bf16(af0, bfg, acc[0][j], 0, 0, 0);
            acc[1][j] = __builtin_amdgcn_mfma_f32_16x16x32_bf16(af1, bfg, acc[1][j], 0, 0, 0);
        }
    }

    // epilogue: +b1, relu, bf16 store.  C/D: col = lane&15, row = quad*4+reg.
#pragma unroll
    for (int j = 0; j < 8; j++) {
        int col = j * 16 + m;
        float bias = b1[col];
#pragma unroll
        for (int i = 0; i < 2; i++) {
#pragma unroll
            for (int r = 0; r < 4; r++) {
                int row = row0 + wave * 32 + i * 16 + quad * 4 + r;
                if (row < N) {
                    float v = fmaxf(acc[i][j][r] + bias, 0.f);
                    h1[(size_t)row * 128 + col] = f2b(v);
                }
            }
        }
    }
}

// ------------------------------------------------------------------- GEMM 2
// [out_self | t2] = h1 @ W2cat; K=128, 80 fused cols. Tile 128 rows x 80 cols.

__global__ __launch_bounds__(256) void gemm2_mfma(
    const unsigned short* __restrict__ h1, const unsigned short* __restrict__ W2t,
    float* __restrict__ out, float* __restrict__ t2, int N) {

    __shared__ unsigned short As[128 * 40];  // 128 rows x 32 k
    __shared__ unsigned short Bs[80 * 40];   // 80 cols x 32 k

    int tid = threadIdx.x;
    int wave = tid >> 6, lane = tid & 63;
    int row0 = blockIdx.x * 128;
    int m = lane & 15, quad = lane >> 4;

    f32x4 acc[2][5];
#pragma unroll
    for (int i = 0; i < 2; i++)
#pragma unroll
        for (int j = 0; j < 5; j++) acc[i][j] = (f32x4){0.f, 0.f, 0.f, 0.f};

    for (int k0 = 0; k0 < 128; k0 += 32) {
        __syncthreads();
        {
            int r = tid >> 1, kk = (tid & 1) * 16;
            int row = row0 + r;
            float4 v0 = make_float4(0, 0, 0, 0), v1 = v0;
            if (row < N) {
                const float4* p = (const float4*)(h1 + (size_t)row * 128 + k0 + kk);
                v0 = p[0]; v1 = p[1];
            }
            *(float4*)&As[r * 40 + kk] = v0;
            *(float4*)&As[r * 40 + kk + 8] = v1;
            if (tid < 160) {
                const float4* q = (const float4*)(W2t + (size_t)r * 128 + k0 + kk);
                float4 w0 = q[0], w1 = q[1];
                *(float4*)&Bs[r * 40 + kk] = w0;
                *(float4*)&Bs[r * 40 + kk + 8] = w1;
            }
        }
        __syncthreads();

        bf16x8 af0 = *(bf16x8*)&As[(wave * 32 + m) * 40 + quad * 8];
        bf16x8 af1 = *(bf16x8*)&As[(wave * 32 + 16 + m) * 40 + quad * 8];
#pragma unroll
        for (int j = 0; j < 5; j++) {
            bf16x8 bfg = *(bf16x8*)&Bs[(j * 16 + m) * 40 + quad * 8];
            acc[0][j] = __builtin_amdgcn_mfma_f32_16x16x32_bf16(af0, bfg, acc[0][j], 0, 0, 0);
            acc[1][j] = __builtin_amdgcn_mfma_f32_16x16x32_bf16(af1, bfg, acc[1][j], 0, 0, 0);
        }
    }

#pragma unroll
    for (int j = 0; j < 5; j++) {
        int col = j * 16 + m;
#pragma unroll
        for (int i = 0; i < 2; i++) {
#pragma unroll
            for (int r = 0; r < 4; r++) {
                int row = row0 + wave * 32 + i * 16 + quad * 4 + r;
                if (row < N) {
                    float v = acc[i][j][r];
                    if (col < 40) out[(size_t)row * 40 + col] = v;
                    else          t2[(size_t)row * 40 + (col - 40)] = v;
                }
            }
        }
    }
}

// ------------------------------------------------------------------ launch

extern "C" void kernel_launch(void* const* d_in, const int* in_sizes, int n_in,
                              void* d_out, int out_size, void* d_ws, size_t ws_size,
                              hipStream_t stream) {
    const float* x   = (const float*)d_in[0];
    const int*   src = (const int*)d_in[1];
    const int*   dst = (const int*)d_in[2];
    const float* W1s = (const float*)d_in[3];
    const float* W1n = (const float*)d_in[4];
    const float* b1  = (const float*)d_in[5];
    const float* W2s = (const float*)d_in[6];
    const float* W2n = (const float*)d_in[7];
    const float* b2  = (const float*)d_in[8];
    float* out = (float*)d_out;

    int N = in_sizes[0] / 128;
    int E = in_sizes[1];

    char* ws = (char*)d_ws;
    int*            deg       = (int*)(ws + OFF_DEG);
    int*            row_start = (int*)(ws + OFF_ROWSTART);
    int*            cursor    = (int*)(ws + OFF_CURSOR);
    int*            tmp       = (int*)(ws + OFF_TMP);
    int*            bsums     = (int*)(ws + OFF_BSUMS);
    int*            boffs     = (int*)(ws + OFF_BOFFS);
    int*            csr_src   = (int*)(ws + OFF_CSR);
    unsigned short* W1t       = (unsigned short*)(ws + OFF_W1T);
    unsigned short* W2t       = (unsigned short*)(ws + OFF_W2T);
    unsigned short* xb        = (unsigned short*)(ws + OFF_XB);
    unsigned short* aggb      = (unsigned short*)(ws + OFF_AGGB);
    unsigned short* h1b       = (unsigned short*)(ws + OFF_H1B);
    float*          t2        = (float*)(ws + OFF_T2);

    hipMemsetAsync(deg, 0, (size_t)N * sizeof(int), stream);
    hipMemsetAsync(cursor, 0, (size_t)N * sizeof(int), stream);

    int nb = (N + 255) / 256;   // 391 for N=100000 (<= 512 required by scan2)

    deg_count<<<(E + 255) / 256, 256, 0, stream>>>(dst, deg, E);
    scan1<<<nb, 256, 0, stream>>>(deg, tmp, bsums, N);
    scan2<<<1, 512, 0, stream>>>(bsums, boffs, nb);
    scan3<<<nb, 256, 0, stream>>>(tmp, boffs, row_start, N, nb);
    csr_fill<<<(E + 255) / 256, 256, 0, stream>>>(src, dst, row_start, cursor, csr_src, E);

    int n8 = N * 128 / 8;
    cast_bf16<<<(n8 + 255) / 256, 256, 0, stream>>>(x, xb, n8);
    prep_w1t<<<128, 256, 0, stream>>>(W1s, W1n, W1t);
    prep_w2t<<<80, 128, 0, stream>>>(W2s, W2n, W2t);

    int aggBlocks = (N * 64 + 255) / 256;
    agg_mean_bf16<<<aggBlocks, 256, 0, stream>>>(xb, row_start, csr_src, aggb, N);
    gemm1_mfma<<<(N + 127) / 128, 256, 0, stream>>>(xb, aggb, W1t, b1, h1b, N);
    gemm2_mfma<<<(N + 127) / 128, 256, 0, stream>>>(h1b, W2t, out, t2, N);
    agg2_add<<<aggBlocks, 256, 0, stream>>>(t2, row_start, csr_src, b2, out, N);
}

// Round 4
// 444.004 us; speedup vs baseline: 2.5446x; 1.3825x over previous
//
#include <hip/hip_runtime.h>

// GraphSAGE 2-layer forward on MI355X.
// Round 4: latency-optimized gathers.
//   agg_mean: 2 edges/wave-iter (half-wave per edge, uint2/lane) + unroll x2
//             -> 4 independent 256B row loads in flight per wave.
//   agg2:     t2 stored as bf16 (halves gather bytes) + same 2-edge/unroll
//             structure; cross-half shfl reduce.
// Rest unchanged: CSR build (hierarchical scan), bf16 cast, transposed bf16
// weights, MFMA 16x16x32 GEMMs, transform-then-aggregate layer 2.

typedef __attribute__((ext_vector_type(8))) short bf16x8;
typedef __attribute__((ext_vector_type(4))) float f32x4;

#define OFF_DEG      (0ull)
#define OFF_ROWSTART (1ull << 20)
#define OFF_CURSOR   (2ull << 20)
#define OFF_TMP      (3ull << 20)                      // 400 KB local prefix
#define OFF_BSUMS    ((3ull << 20) + (512ull << 10))
#define OFF_BOFFS    ((3ull << 20) + (576ull << 10))
#define OFF_CSR      (4ull << 20)                      // 6.4 MB
#define OFF_W1T      (11ull << 20)                     // 64 KB
#define OFF_W2T      (12ull << 20)                     // 20 KB
#define OFF_XB       (13ull << 20)                     // 25.6 MB
#define OFF_AGGB     (39ull << 20)                     // 25.6 MB
#define OFF_H1B      (65ull << 20)                     // 25.6 MB
#define OFF_T2       (91ull << 20)                     // 8 MB (bf16 now)

static __device__ __forceinline__ unsigned short f2b(float f) {
    unsigned int u = __float_as_uint(f);
    u += 0x7fffu + ((u >> 16) & 1u);   // round-to-nearest-even
    return (unsigned short)(u >> 16);
}
static __device__ __forceinline__ float blo(unsigned int v) { return __uint_as_float(v << 16); }
static __device__ __forceinline__ float bhi(unsigned int v) { return __uint_as_float(v & 0xffff0000u); }

// ---------------------------------------------------------------- CSR build

__global__ void deg_count(const int* __restrict__ dst, int* __restrict__ deg, int E) {
    int e = blockIdx.x * blockDim.x + threadIdx.x;
    if (e < E) atomicAdd(&deg[dst[e]], 1);
}

__global__ void scan1(const int* __restrict__ deg, int* __restrict__ tmp,
                      int* __restrict__ bsums, int N) {
    __shared__ int s[256];
    int t = threadIdx.x;
    int i = blockIdx.x * 256 + t;
    int v = (i < N) ? deg[i] : 0;
    s[t] = v;
    __syncthreads();
    for (int off = 1; off < 256; off <<= 1) {
        int u = (t >= off) ? s[t - off] : 0;
        __syncthreads();
        s[t] += u;
        __syncthreads();
    }
    if (i < N) tmp[i] = s[t] - v;
    if (t == 255) bsums[blockIdx.x] = s[t];
}

__global__ void scan2(const int* __restrict__ bsums, int* __restrict__ boffs, int nb) {
    __shared__ int s[512];
    int t = threadIdx.x;
    int v = (t < nb) ? bsums[t] : 0;
    s[t] = v;
    __syncthreads();
    for (int off = 1; off < 512; off <<= 1) {
        int u = (t >= off) ? s[t - off] : 0;
        __syncthreads();
        s[t] += u;
        __syncthreads();
    }
    if (t < nb) boffs[t] = s[t] - v;
    if (t == 511) boffs[nb] = s[t];
}

__global__ void scan3(const int* __restrict__ tmp, const int* __restrict__ boffs,
                      int* __restrict__ row_start, int N, int nb) {
    int i = blockIdx.x * 256 + threadIdx.x;
    if (i < N) row_start[i] = tmp[i] + boffs[blockIdx.x];
    if (i == 0) row_start[N] = boffs[nb];
}

__global__ void csr_fill(const int* __restrict__ src, const int* __restrict__ dst,
                         const int* __restrict__ row_start, int* __restrict__ cursor,
                         int* __restrict__ csr_src, int E) {
    int e = blockIdx.x * blockDim.x + threadIdx.x;
    if (e < E) {
        int d = dst[e];
        int slot = atomicAdd(&cursor[d], 1);
        csr_src[row_start[d] + slot] = src[e];
    }
}

// ------------------------------------------------------------- prep kernels

__global__ void cast_bf16(const float* __restrict__ x, unsigned short* __restrict__ xb, int n8) {
    int i = blockIdx.x * blockDim.x + threadIdx.x;
    if (i >= n8) return;
    const float4* p = (const float4*)x + (size_t)i * 2;
    float4 v0 = p[0], v1 = p[1];
    unsigned short o[8];
    o[0] = f2b(v0.x); o[1] = f2b(v0.y); o[2] = f2b(v0.z); o[3] = f2b(v0.w);
    o[4] = f2b(v1.x); o[5] = f2b(v1.y); o[6] = f2b(v1.z); o[7] = f2b(v1.w);
    *(float4*)(xb + (size_t)i * 8) = *(float4*)o;
}

__global__ void prep_w1t(const float* __restrict__ W1s, const float* __restrict__ W1n,
                         unsigned short* __restrict__ W1t) {
    int c = blockIdx.x, k = threadIdx.x;
    float v = (k < 128) ? W1s[(size_t)k * 128 + c] : W1n[(size_t)(k - 128) * 128 + c];
    W1t[(size_t)c * 256 + k] = f2b(v);
}

__global__ void prep_w2t(const float* __restrict__ W2s, const float* __restrict__ W2n,
                         unsigned short* __restrict__ W2t) {
    int c = blockIdx.x, k = threadIdx.x;
    float v = (c < 40) ? W2s[(size_t)k * 40 + c] : W2n[(size_t)k * 40 + (c - 40)];
    W2t[(size_t)c * 128 + k] = f2b(v);
}

// ------------------------------------------------------- aggregation kernels

// One wave per node, TWO edges per iteration: half-wave h handles edge e+h.
// Lane (l = lane&31) owns dims 4l..4l+3 via one uint2 (8B) load -> a full
// 256B row per half-wave per instruction. Unroll x2 -> 4 rows in flight.
__global__ void agg_mean_bf16(const unsigned short* __restrict__ xb,
                              const int* __restrict__ row_start,
                              const int* __restrict__ csr_src,
                              unsigned short* __restrict__ aggb, int N) {
    int wave = (blockIdx.x * blockDim.x + threadIdx.x) >> 6;
    int lane = threadIdx.x & 63;
    if (wave >= N) return;
    int half = lane >> 5;      // which edge of the pair
    int l = lane & 31;         // dim group (4 dims)
    int beg = row_start[wave], end = row_start[wave + 1];
    const uint2* x4 = (const uint2*)xb;   // row = 32 uint2

    float a0 = 0.f, a1 = 0.f, a2 = 0.f, a3 = 0.f;
    int e = beg + half;
    for (; e + 2 < end; e += 4) {         // this lane: edges e and e+2
        int s0 = csr_src[e];
        int s1 = csr_src[e + 2];
        uint2 v0 = x4[(size_t)s0 * 32 + l];
        uint2 v1 = x4[(size_t)s1 * 32 + l];
        a0 += blo(v0.x) + blo(v1.x);
        a1 += bhi(v0.x) + bhi(v1.x);
        a2 += blo(v0.y) + blo(v1.y);
        a3 += bhi(v0.y) + bhi(v1.y);
    }
    for (; e < end; e += 2) {
        int s = csr_src[e];
        uint2 v = x4[(size_t)s * 32 + l];
        a0 += blo(v.x); a1 += bhi(v.x); a2 += blo(v.y); a3 += bhi(v.y);
    }
    // cross-half reduce (lane l += lane l+32)
    a0 += __shfl_xor(a0, 32);
    a1 += __shfl_xor(a1, 32);
    a2 += __shfl_xor(a2, 32);
    a3 += __shfl_xor(a3, 32);
    if (half == 0) {
        float inv = 1.0f / fmaxf((float)(end - beg), 1.0f);
        uint2 o;
        o.x = (unsigned int)f2b(a0 * inv) | ((unsigned int)f2b(a1 * inv) << 16);
        o.y = (unsigned int)f2b(a2 * inv) | ((unsigned int)f2b(a3 * inv) << 16);
        ((uint2*)aggb)[(size_t)wave * 32 + l] = o;
    }
}

// One wave per node, two edges/iter over bf16 t2 (40 dims = 20 uints, 80B/row).
// Lane l<20 owns dims 2l,2l+1. out[n][c] += mean(t2[nbrs][c]) + b2[c].
__global__ void agg2_add(const unsigned short* __restrict__ t2b,
                         const int* __restrict__ row_start,
                         const int* __restrict__ csr_src, const float* __restrict__ b2,
                         float* __restrict__ out, int N) {
    int wave = (blockIdx.x * blockDim.x + threadIdx.x) >> 6;
    int lane = threadIdx.x & 63;
    if (wave >= N) return;
    int half = lane >> 5;
    int l = lane & 31;
    int beg = row_start[wave], end = row_start[wave + 1];
    const unsigned int* t2u = (const unsigned int*)t2b;   // row = 20 uints

    float a0 = 0.f, a1 = 0.f;
    if (l < 20) {
        int e = beg + half;
        for (; e + 2 < end; e += 4) {
            int s0 = csr_src[e];
            int s1 = csr_src[e + 2];
            unsigned int v0 = t2u[(size_t)s0 * 20 + l];
            unsigned int v1 = t2u[(size_t)s1 * 20 + l];
            a0 += blo(v0) + blo(v1);
            a1 += bhi(v0) + bhi(v1);
        }
        for (; e < end; e += 2) {
            unsigned int v = t2u[(size_t)csr_src[e] * 20 + l];
            a0 += blo(v); a1 += bhi(v);
        }
    }
    a0 += __shfl_xor(a0, 32);
    a1 += __shfl_xor(a1, 32);
    if (half == 0 && l < 20) {
        float inv = 1.0f / fmaxf((float)(end - beg), 1.0f);
        float2 bb = ((const float2*)b2)[l];
        float2* op = (float2*)(out + (size_t)wave * 40 + 2 * l);
        float2 cur = *op;
        cur.x += a0 * inv + bb.x;
        cur.y += a1 * inv + bb.y;
        *op = cur;
    }
}

// ------------------------------------------------------------------- GEMM 1
// h1 = relu([xb|aggb] @ W1cat + b1); K=256, 128 cols. MFMA 16x16x32 bf16.

__global__ __launch_bounds__(256) void gemm1_mfma(
    const unsigned short* __restrict__ xb, const unsigned short* __restrict__ aggb,
    const unsigned short* __restrict__ W1t, const float* __restrict__ b1,
    unsigned short* __restrict__ h1, int N) {

    __shared__ unsigned short As[128 * 40];
    __shared__ unsigned short Bs[128 * 40];

    int tid = threadIdx.x;
    int wave = tid >> 6, lane = tid & 63;
    int row0 = blockIdx.x * 128;
    int m = lane & 15, quad = lane >> 4;

    f32x4 acc[2][8];
#pragma unroll
    for (int i = 0; i < 2; i++)
#pragma unroll
        for (int j = 0; j < 8; j++) acc[i][j] = (f32x4){0.f, 0.f, 0.f, 0.f};

    for (int k0 = 0; k0 < 256; k0 += 32) {
        __syncthreads();
        {
            int r = tid >> 1, kk = (tid & 1) * 16;
            int row = row0 + r;
            float4 v0 = make_float4(0, 0, 0, 0), v1 = v0;
            if (row < N) {
                const unsigned short* s = (k0 < 128)
                    ? (xb + (size_t)row * 128 + k0 + kk)
                    : (aggb + (size_t)row * 128 + (k0 - 128) + kk);
                const float4* p = (const float4*)s;
                v0 = p[0]; v1 = p[1];
            }
            *(float4*)&As[r * 40 + kk] = v0;
            *(float4*)&As[r * 40 + kk + 8] = v1;
            const float4* q = (const float4*)(W1t + (size_t)r * 256 + k0 + kk);
            float4 w0 = q[0], w1 = q[1];
            *(float4*)&Bs[r * 40 + kk] = w0;
            *(float4*)&Bs[r * 40 + kk + 8] = w1;
        }
        __syncthreads();

        bf16x8 af0 = *(bf16x8*)&As[(wave * 32 + m) * 40 + quad * 8];
        bf16x8 af1 = *(bf16x8*)&As[(wave * 32 + 16 + m) * 40 + quad * 8];
#pragma unroll
        for (int j = 0; j < 8; j++) {
            bf16x8 bfg = *(bf16x8*)&Bs[(j * 16 + m) * 40 + quad * 8];
            acc[0][j] = __builtin_amdgcn_mfma_f32_16x16x32_bf16(af0, bfg, acc[0][j], 0, 0, 0);
            acc[1][j] = __builtin_amdgcn_mfma_f32_16x16x32_bf16(af1, bfg, acc[1][j], 0, 0, 0);
        }
    }

#pragma unroll
    for (int j = 0; j < 8; j++) {
        int col = j * 16 + m;
        float bias = b1[col];
#pragma unroll
        for (int i = 0; i < 2; i++) {
#pragma unroll
            for (int r = 0; r < 4; r++) {
                int row = row0 + wave * 32 + i * 16 + quad * 4 + r;
                if (row < N) {
                    float v = fmaxf(acc[i][j][r] + bias, 0.f);
                    h1[(size_t)row * 128 + col] = f2b(v);
                }
            }
        }
    }
}

// ------------------------------------------------------------------- GEMM 2
// [out_self | t2(bf16)] = h1 @ W2cat; K=128, 80 fused cols.

__global__ __launch_bounds__(256) void gemm2_mfma(
    const unsigned short* __restrict__ h1, const unsigned short* __restrict__ W2t,
    float* __restrict__ out, unsigned short* __restrict__ t2b, int N) {

    __shared__ unsigned short As[128 * 40];
    __shared__ unsigned short Bs[80 * 40];

    int tid = threadIdx.x;
    int wave = tid >> 6, lane = tid & 63;
    int row0 = blockIdx.x * 128;
    int m = lane & 15, quad = lane >> 4;

    f32x4 acc[2][5];
#pragma unroll
    for (int i = 0; i < 2; i++)
#pragma unroll
        for (int j = 0; j < 5; j++) acc[i][j] = (f32x4){0.f, 0.f, 0.f, 0.f};

    for (int k0 = 0; k0 < 128; k0 += 32) {
        __syncthreads();
        {
            int r = tid >> 1, kk = (tid & 1) * 16;
            int row = row0 + r;
            float4 v0 = make_float4(0, 0, 0, 0), v1 = v0;
            if (row < N) {
                const float4* p = (const float4*)(h1 + (size_t)row * 128 + k0 + kk);
                v0 = p[0]; v1 = p[1];
            }
            *(float4*)&As[r * 40 + kk] = v0;
            *(float4*)&As[r * 40 + kk + 8] = v1;
            if (tid < 160) {
                const float4* q = (const float4*)(W2t + (size_t)r * 128 + k0 + kk);
                float4 w0 = q[0], w1 = q[1];
                *(float4*)&Bs[r * 40 + kk] = w0;
                *(float4*)&Bs[r * 40 + kk + 8] = w1;
            }
        }
        __syncthreads();

        bf16x8 af0 = *(bf16x8*)&As[(wave * 32 + m) * 40 + quad * 8];
        bf16x8 af1 = *(bf16x8*)&As[(wave * 32 + 16 + m) * 40 + quad * 8];
#pragma unroll
        for (int j = 0; j < 5; j++) {
            bf16x8 bfg = *(bf16x8*)&Bs[(j * 16 + m) * 40 + quad * 8];
            acc[0][j] = __builtin_amdgcn_mfma_f32_16x16x32_bf16(af0, bfg, acc[0][j], 0, 0, 0);
            acc[1][j] = __builtin_amdgcn_mfma_f32_16x16x32_bf16(af1, bfg, acc[1][j], 0, 0, 0);
        }
    }

#pragma unroll
    for (int j = 0; j < 5; j++) {
        int col = j * 16 + m;
#pragma unroll
        for (int i = 0; i < 2; i++) {
#pragma unroll
            for (int r = 0; r < 4; r++) {
                int row = row0 + wave * 32 + i * 16 + quad * 4 + r;
                if (row < N) {
                    float v = acc[i][j][r];
                    if (col < 40) out[(size_t)row * 40 + col] = v;
                    else          t2b[(size_t)row * 40 + (col - 40)] = f2b(v);
                }
            }
        }
    }
}

// ------------------------------------------------------------------ launch

extern "C" void kernel_launch(void* const* d_in, const int* in_sizes, int n_in,
                              void* d_out, int out_size, void* d_ws, size_t ws_size,
                              hipStream_t stream) {
    const float* x   = (const float*)d_in[0];
    const int*   src = (const int*)d_in[1];
    const int*   dst = (const int*)d_in[2];
    const float* W1s = (const float*)d_in[3];
    const float* W1n = (const float*)d_in[4];
    const float* b1  = (const float*)d_in[5];
    const float* W2s = (const float*)d_in[6];
    const float* W2n = (const float*)d_in[7];
    const float* b2  = (const float*)d_in[8];
    float* out = (float*)d_out;

    int N = in_sizes[0] / 128;
    int E = in_sizes[1];

    char* ws = (char*)d_ws;
    int*            deg       = (int*)(ws + OFF_DEG);
    int*            row_start = (int*)(ws + OFF_ROWSTART);
    int*            cursor    = (int*)(ws + OFF_CURSOR);
    int*            tmp       = (int*)(ws + OFF_TMP);
    int*            bsums     = (int*)(ws + OFF_BSUMS);
    int*            boffs     = (int*)(ws + OFF_BOFFS);
    int*            csr_src   = (int*)(ws + OFF_CSR);
    unsigned short* W1t       = (unsigned short*)(ws + OFF_W1T);
    unsigned short* W2t       = (unsigned short*)(ws + OFF_W2T);
    unsigned short* xb        = (unsigned short*)(ws + OFF_XB);
    unsigned short* aggb      = (unsigned short*)(ws + OFF_AGGB);
    unsigned short* h1b       = (unsigned short*)(ws + OFF_H1B);
    unsigned short* t2b       = (unsigned short*)(ws + OFF_T2);

    hipMemsetAsync(deg, 0, (size_t)N * sizeof(int), stream);
    hipMemsetAsync(cursor, 0, (size_t)N * sizeof(int), stream);

    int nb = (N + 255) / 256;   // 391 for N=100000

    deg_count<<<(E + 255) / 256, 256, 0, stream>>>(dst, deg, E);
    scan1<<<nb, 256, 0, stream>>>(deg, tmp, bsums, N);
    scan2<<<1, 512, 0, stream>>>(bsums, boffs, nb);
    scan3<<<nb, 256, 0, stream>>>(tmp, boffs, row_start, N, nb);
    csr_fill<<<(E + 255) / 256, 256, 0, stream>>>(src, dst, row_start, cursor, csr_src, E);

    int n8 = N * 128 / 8;
    cast_bf16<<<(n8 + 255) / 256, 256, 0, stream>>>(x, xb, n8);
    prep_w1t<<<128, 256, 0, stream>>>(W1s, W1n, W1t);
    prep_w2t<<<80, 128, 0, stream>>>(W2s, W2n, W2t);

    int aggBlocks = (N * 64 + 255) / 256;
    agg_mean_bf16<<<aggBlocks, 256, 0, stream>>>(xb, row_start, csr_src, aggb, N);
    gemm1_mfma<<<(N + 127) / 128, 256, 0, stream>>>(xb, aggb, W1t, b1, h1b, N);
    gemm2_mfma<<<(N + 127) / 128, 256, 0, stream>>>(h1b, W2t, out, t2b, N);
    agg2_add<<<aggBlocks, 256, 0, stream>>>(t2b, row_start, csr_src, b2, out, N);
}